// Round 8
// baseline (81.953 us; speedup 1.0000x reference)
//
#include <hip/hip_runtime.h>
#include <math.h>

#define B_ 4
#define T_ 512
#define C_ 128
#define HS_ 64

typedef float f4 __attribute__((ext_vector_type(4)));

// scale = C^-0.5
#define SCALE_ 0.08838834764831845f

// ---------------------------------------------------------------------------
// Kernel 1: prep.  x1 = x + pos_emb;  Aq = x1@W1q + b1;  Ak = x1@W1k; V = x@Wv
// 256 blocks x 640 threads (10 waves). Block = 8 rows.  (unchanged)
// ---------------------------------------------------------------------------
__global__ __launch_bounds__(640) void k_prep(
    const float* __restrict__ x, const float* __restrict__ pos,
    const float* __restrict__ W1, const float* __restrict__ b1,
    const float* __restrict__ Wv,
    float* __restrict__ Aq, float* __restrict__ Ak, float* __restrict__ V)
{
    __shared__ float x1s[8 * 132];
    __shared__ float xs[8 * 132];
    const int t = threadIdx.x;
    const int row0 = blockIdx.x * 8;  // over B*T = 2048

    if (t < 256) {
        int r = t >> 5, cq = t & 31;
        int gr = row0 + r;
        f4 xv = *(const f4*)(x + gr * 128 + cq * 4);
        f4 pv = *(const f4*)(pos + (gr & 511) * 128 + cq * 4);
        *(f4*)&xs[r * 132 + cq * 4] = xv;
        *(f4*)&x1s[r * 132 + cq * 4] = xv + pv;
    }
    __syncthreads();

    const int q = t >> 3;   // 0..79 col-quad
    const int r = t & 7;    // row in tile

    const float* wbase;
    int wstr, col0;
    const float* xb;
    float* obase;
    int ostr;
    f4 binit = {0.f, 0.f, 0.f, 0.f};
    if (q < 32) {
        col0 = q * 4;
        wbase = W1 + 128 * 128 + col0;  // W1q rows (c-major)
        wstr = 128;
        xb = x1s;
        obase = Aq;
        ostr = 128;
        binit = *(const f4*)(b1 + col0);
    } else if (q < 64) {
        col0 = (q - 32) * 4;
        wbase = W1 + col0;  // W1k rows
        wstr = 128;
        xb = x1s;
        obase = Ak;
        ostr = 128;
    } else {
        col0 = (q - 64) * 4;
        wbase = Wv + col0;
        wstr = 64;
        xb = xs;
        obase = V;
        ostr = 64;
    }

    f4 acc = binit;
    const float* xr = xb + r * 132;
#pragma unroll 8
    for (int c = 0; c < 128; ++c) {
        f4 w = *(const f4*)(wbase + c * wstr);
        acc += xr[c] * w;
    }

    int gr = row0 + r;
    *(f4*)(obase + gr * ostr + col0) = acc;
}

// ---------------------------------------------------------------------------
// Kernel 2: fused wei + causal softmax + PV — barrier-free per-wave flash.
// Block = 256 thr = 4 waves = 2 adjacent query rows x 2 j-splits.
//
// rule #20, strong form: the hoisted Aq row-half lives in SIXTEEN NAMED f4
// VARIABLES (aq0..aq15), not an array. Rounds 5-7 showed hipcc keeps an
// f4[16] array (even fully-unrolled-indexed) partially in SCRATCH across a
// long loop live range: VGPR_Count 48/84, 39-66MB HBM writes of spill
// traffic per dispatch. Named values are plain SSA -> register-allocated.
// ---------------------------------------------------------------------------
__global__ __launch_bounds__(256, 3) void k_fused(
    const float* __restrict__ Aq, const float* __restrict__ Ak,
    const float* __restrict__ V, const float* __restrict__ W2,
    float* __restrict__ out)
{
    __shared__ float w2s[128];
    __shared__ float pbuf[4][32];
    __shared__ float mls[4][2];
    __shared__ float accs[4][64];

    const int t = threadIdx.x;
    const int w = t >> 6;
    const int lane = t & 63;
    const int bx = blockIdx.x;            // 0..1023
    const int b = bx & 3;
    const int g = 255 - (bx >> 2);        // descending row-pair
    const int row = g * 2 + (w >> 1);
    const int split = w & 1;

    if (t < 32) *(f4*)&w2s[t * 4] = *(const f4*)(W2 + t * 4);
    __syncthreads();

    const int j2 = lane >> 1;
    const int half = lane & 1;

    // hoist Aq row half into 16 NAMED f4 registers
    const float* aqrow = Aq + (size_t)(b * T_ + row) * C_ + half * 64;
    const f4 aq0  = *(const f4*)(aqrow + 0);
    const f4 aq1  = *(const f4*)(aqrow + 4);
    const f4 aq2  = *(const f4*)(aqrow + 8);
    const f4 aq3  = *(const f4*)(aqrow + 12);
    const f4 aq4  = *(const f4*)(aqrow + 16);
    const f4 aq5  = *(const f4*)(aqrow + 20);
    const f4 aq6  = *(const f4*)(aqrow + 24);
    const f4 aq7  = *(const f4*)(aqrow + 28);
    const f4 aq8  = *(const f4*)(aqrow + 32);
    const f4 aq9  = *(const f4*)(aqrow + 36);
    const f4 aq10 = *(const f4*)(aqrow + 40);
    const f4 aq11 = *(const f4*)(aqrow + 44);
    const f4 aq12 = *(const f4*)(aqrow + 48);
    const f4 aq13 = *(const f4*)(aqrow + 52);
    const f4 aq14 = *(const f4*)(aqrow + 56);
    const f4 aq15 = *(const f4*)(aqrow + 60);

    const float* w2h = &w2s[half * 64];
    const float* akb = Ak + (size_t)b * T_ * C_;
    const float* vb  = V + (size_t)b * T_ * HS_;

    float m = -1e30f, l = 0.f, acc = 0.f;
    const int jtm = row >> 5;

    for (int jt = split; jt <= jtm; jt += 2) {
        // ---- S for j = jt*32 + j2 over this lane's c-half ----
        const float* akrow = akb + (size_t)(jt * 32 + j2) * C_ + half * 64;
        f4 a4 = {0.f, 0.f, 0.f, 0.f};
#define STEP_(U, AQ)                                                  \
        {                                                             \
            f4 kk = *(const f4*)(akrow + (U) * 4);                    \
            f4 wv = *(const f4*)(w2h + (U) * 4);                      \
            f4 tt = (AQ) + kk;                                        \
            tt.x = fmaxf(tt.x, 0.f);                                  \
            tt.y = fmaxf(tt.y, 0.f);                                  \
            tt.z = fmaxf(tt.z, 0.f);                                  \
            tt.w = fmaxf(tt.w, 0.f);                                  \
            a4 += tt * wv;                                            \
        }
        STEP_(0, aq0)   STEP_(1, aq1)   STEP_(2, aq2)   STEP_(3, aq3)
        STEP_(4, aq4)   STEP_(5, aq5)   STEP_(6, aq6)   STEP_(7, aq7)
        STEP_(8, aq8)   STEP_(9, aq9)   STEP_(10, aq10) STEP_(11, aq11)
        STEP_(12, aq12) STEP_(13, aq13) STEP_(14, aq14) STEP_(15, aq15)
#undef STEP_
        float s = (a4.x + a4.y) + (a4.z + a4.w);
        s += __shfl_xor(s, 1);            // combine halves -> full-c dot
        s *= SCALE_;
        const int gj = jt * 32 + j2;
        if (gj > row) s = -1e30f;         // causal mask

        // ---- online softmax (within wave) ----
        float tm = s;
#pragma unroll
        for (int off = 2; off < 64; off <<= 1) tm = fmaxf(tm, __shfl_xor(tm, off));
        const float mn = fmaxf(m, tm);
        const float alpha = __expf(m - mn);
        const float p = __expf(s - mn);   // masked -> 0
        if (!half) pbuf[w][j2] = p;       // within-wave visible (lgkmcnt)
        float ls = p;
#pragma unroll
        for (int off = 1; off < 64; off <<= 1) ls += __shfl_xor(ls, off);
        l = l * alpha + 0.5f * ls;        // pair-duplicated sum
        m = mn;

        // ---- PV: acc[h=lane] ----
        const float* vt = vb + (size_t)(jt * 32) * HS_ + lane;
        float t0 = 0.f, t1 = 0.f, t2 = 0.f, t3 = 0.f;
#pragma unroll
        for (int jj = 0; jj < 32; jj += 4) {
            t0 += pbuf[w][jj]     * vt[(jj)     * HS_];
            t1 += pbuf[w][jj + 1] * vt[(jj + 1) * HS_];
            t2 += pbuf[w][jj + 2] * vt[(jj + 2) * HS_];
            t3 += pbuf[w][jj + 3] * vt[(jj + 3) * HS_];
        }
        acc = acc * alpha + ((t0 + t1) + (t2 + t3));
    }

    // ---- split merge ----
    if (lane == 0) { mls[w][0] = m; mls[w][1] = l; }
    accs[w][lane] = acc;
    __syncthreads();

    if (!(w & 1)) {
        const float m1 = mls[w + 1][0], l1 = mls[w + 1][1];
        const float a1 = accs[w + 1][lane];
        const float ms = fmaxf(m, m1);
        const float e0 = __expf(m - ms), e1 = __expf(m1 - ms);
        const float num = acc * e0 + a1 * e1;
        const float den = l * e0 + l1 * e1;
        out[(size_t)(b * T_ + row) * HS_ + lane] = num / den;
    }
}

// ---------------------------------------------------------------------------
extern "C" void kernel_launch(void* const* d_in, const int* in_sizes, int n_in,
                              void* d_out, int out_size, void* d_ws, size_t ws_size,
                              hipStream_t stream)
{
    const float* x   = (const float*)d_in[0];
    const float* pos = (const float*)d_in[1];
    const float* W1  = (const float*)d_in[2];
    const float* b1  = (const float*)d_in[3];
    const float* W2  = (const float*)d_in[4];
    const float* b2  = (const float*)d_in[5];  (void)b2;  // cancels in softmax
    const float* Wv  = (const float*)d_in[6];
    float* out = (float*)d_out;
    float* ws = (float*)d_ws;

    float* Aq = ws;                 // B*T*C = 262144
    float* Ak = ws + 262144;        // 262144
    float* V  = ws + 524288;        // B*T*HS = 131072

    k_prep<<<dim3(256), dim3(640), 0, stream>>>(x, pos, W1, b1, Wv, Aq, Ak, V);
    k_fused<<<dim3(1024), dim3(256), 0, stream>>>(Aq, Ak, V, W2, out);
}

// Round 9
// 52.125 us; speedup vs baseline: 1.5722x; 1.5722x over previous
//
#include <hip/hip_runtime.h>
#include <math.h>

#define B_ 4
#define T_ 512
#define C_ 128
#define HS_ 64

typedef float f4 __attribute__((ext_vector_type(4)));

// scale = C^-0.5
#define SCALE_ 0.08838834764831845f

// ---------------------------------------------------------------------------
// Kernel 1: prep.  x1 = x + pos_emb;  Aq = x1@W1q + b1;  Ak = x1@W1k; V = x@Wv
// 256 blocks x 640 threads (10 waves). Block = 8 rows.  (unchanged)
// ---------------------------------------------------------------------------
__global__ __launch_bounds__(640) void k_prep(
    const float* __restrict__ x, const float* __restrict__ pos,
    const float* __restrict__ W1, const float* __restrict__ b1,
    const float* __restrict__ Wv,
    float* __restrict__ Aq, float* __restrict__ Ak, float* __restrict__ V)
{
    __shared__ float x1s[8 * 132];
    __shared__ float xs[8 * 132];
    const int t = threadIdx.x;
    const int row0 = blockIdx.x * 8;  // over B*T = 2048

    if (t < 256) {
        int r = t >> 5, cq = t & 31;
        int gr = row0 + r;
        f4 xv = *(const f4*)(x + gr * 128 + cq * 4);
        f4 pv = *(const f4*)(pos + (gr & 511) * 128 + cq * 4);
        *(f4*)&xs[r * 132 + cq * 4] = xv;
        *(f4*)&x1s[r * 132 + cq * 4] = xv + pv;
    }
    __syncthreads();

    const int q = t >> 3;   // 0..79 col-quad
    const int r = t & 7;    // row in tile

    const float* wbase;
    int wstr, col0;
    const float* xb;
    float* obase;
    int ostr;
    f4 binit = {0.f, 0.f, 0.f, 0.f};
    if (q < 32) {
        col0 = q * 4;
        wbase = W1 + 128 * 128 + col0;  // W1q rows (c-major)
        wstr = 128;
        xb = x1s;
        obase = Aq;
        ostr = 128;
        binit = *(const f4*)(b1 + col0);
    } else if (q < 64) {
        col0 = (q - 32) * 4;
        wbase = W1 + col0;  // W1k rows
        wstr = 128;
        xb = x1s;
        obase = Ak;
        ostr = 128;
    } else {
        col0 = (q - 64) * 4;
        wbase = Wv + col0;
        wstr = 64;
        xb = xs;
        obase = V;
        ostr = 64;
    }

    f4 acc = binit;
    const float* xr = xb + r * 132;
#pragma unroll 8
    for (int c = 0; c < 128; ++c) {
        f4 w = *(const f4*)(wbase + c * wstr);
        acc += xr[c] * w;
    }

    int gr = row0 + r;
    *(f4*)(obase + gr * ostr + col0) = acc;
}

// ---------------------------------------------------------------------------
// Kernel 2: fused wei + causal softmax + PV — barrier-free per-wave flash.
// Block = 256 thr = 4 waves = ONE query row x 4 j-splits. Grid 2048
// (8 waves/SIMD potential). NO __syncthreads in the loop.
//
// COALESCING (the round-8 lesson): per u, ONE load instruction reads TWO
// COMPLETE Ak rows (1KB contiguous, 16 lines) via lane=(hi=lane>>5,
// cc=lane&31): kk = Ak[jt*32+2u+hi][cc*4..+4]. Rounds 4-8 had each load
// touching 64 scattered lines (TA-serialized, ~29us/CU of address
// processing). The c-reduce is 5 shfl_xor over the 32 cc-lanes; the 16
// u-chains are independent -> pipelined.
// Per-lane hoists are now just aq f4 + w2 f4 (VGPR ~60, no spill risk).
// ---------------------------------------------------------------------------
__global__ __launch_bounds__(256, 4) void k_fused(
    const float* __restrict__ Aq, const float* __restrict__ Ak,
    const float* __restrict__ V, const float* __restrict__ W2,
    float* __restrict__ out)
{
    __shared__ float pbuf[4][32];
    __shared__ float mls[4][2];
    __shared__ float accs[4][64];

    const int t = threadIdx.x;
    const int w = t >> 6;             // wave = j-split 0..3
    const int lane = t & 63;
    const int bx = blockIdx.x;        // 0..2047
    const int b = bx & 3;
    const int row = 511 - (bx >> 2);  // descending: heavy rows first

    const int cc = lane & 31;         // c-chunk selector (4 floats)
    const int hi = lane >> 5;         // row-within-pair for kk loads

    // per-lane hoists: one f4 of Aq[row] and one f4 of W2
    const f4 aqc = *(const f4*)(Aq + (size_t)(b * T_ + row) * C_ + cc * 4);
    const f4 w2c = *(const f4*)(W2 + cc * 4);

    const float* akb = Ak + (size_t)b * T_ * C_;
    const float* vb  = V + (size_t)b * T_ * HS_;

    float m = -1e30f, l = 0.f, acc = 0.f;
    const int jtm = row >> 5;

    for (int jt = w; jt <= jtm; jt += 4) {
        const float* aktile = akb + (size_t)(jt * 32) * C_;

        // ---- S partials: u-th load = rows {2u, 2u+1}, contiguous 1KB ----
#pragma unroll
        for (int u = 0; u < 16; ++u) {
            f4 kk = *(const f4*)(aktile + (2 * u + hi) * C_ + cc * 4);
            f4 tt = aqc + kk;
            tt.x = fmaxf(tt.x, 0.f);
            tt.y = fmaxf(tt.y, 0.f);
            tt.z = fmaxf(tt.z, 0.f);
            tt.w = fmaxf(tt.w, 0.f);
            float s = tt.x * w2c.x + tt.y * w2c.y + tt.z * w2c.z + tt.w * w2c.w;
            s += __shfl_xor(s, 1);
            s += __shfl_xor(s, 2);
            s += __shfl_xor(s, 4);
            s += __shfl_xor(s, 8);
            s += __shfl_xor(s, 16);       // full c-sum in all 32 cc-lanes
            if (cc == u) pbuf[w][2 * u + hi] = s;
        }

        // ---- online softmax (within wave); lane's j = cc ----
        float sv = pbuf[w][cc] * SCALE_;
        const int gj = jt * 32 + cc;
        if (gj > row) sv = -1e30f;        // causal mask
        float tm = sv;
        tm = fmaxf(tm, __shfl_xor(tm, 1));
        tm = fmaxf(tm, __shfl_xor(tm, 2));
        tm = fmaxf(tm, __shfl_xor(tm, 4));
        tm = fmaxf(tm, __shfl_xor(tm, 8));
        tm = fmaxf(tm, __shfl_xor(tm, 16));
        const float mn = fmaxf(m, tm);
        const float alpha = __expf(m - mn);
        const float p = __expf(sv - mn);  // masked -> 0
        if (lane < 32) pbuf[w][lane] = p;
        float ls = p;
        ls += __shfl_xor(ls, 1);
        ls += __shfl_xor(ls, 2);
        ls += __shfl_xor(ls, 4);
        ls += __shfl_xor(ls, 8);
        ls += __shfl_xor(ls, 16);
        l = l * alpha + ls;
        m = mn;

        // ---- PV: acc[h=lane]; p via broadcast f4 LDS reads ----
        const float* vt = vb + (size_t)(jt * 32) * HS_ + lane;
        float t0 = 0.f, t1 = 0.f, t2 = 0.f, t3 = 0.f;
#pragma unroll
        for (int q8 = 0; q8 < 8; ++q8) {
            f4 p4 = *(const f4*)&pbuf[w][q8 * 4];
            t0 += p4.x * vt[(q8 * 4 + 0) * HS_];
            t1 += p4.y * vt[(q8 * 4 + 1) * HS_];
            t2 += p4.z * vt[(q8 * 4 + 2) * HS_];
            t3 += p4.w * vt[(q8 * 4 + 3) * HS_];
        }
        acc = acc * alpha + ((t0 + t1) + (t2 + t3));
    }

    // ---- 4-way split merge ----
    if (lane == 0) { mls[w][0] = m; mls[w][1] = l; }
    accs[w][lane] = acc;
    __syncthreads();

    if (w == 0) {
        const float m0 = mls[0][0], m1 = mls[1][0], m2 = mls[2][0], m3 = mls[3][0];
        const float ms = fmaxf(fmaxf(m0, m1), fmaxf(m2, m3));
        const float e0 = __expf(m0 - ms), e1 = __expf(m1 - ms);
        const float e2 = __expf(m2 - ms), e3 = __expf(m3 - ms);
        const float num = accs[0][lane] * e0 + accs[1][lane] * e1 +
                          accs[2][lane] * e2 + accs[3][lane] * e3;
        const float den = mls[0][1] * e0 + mls[1][1] * e1 +
                          mls[2][1] * e2 + mls[3][1] * e3;
        out[(size_t)(b * T_ + row) * HS_ + lane] = num / den;
    }
}

// ---------------------------------------------------------------------------
extern "C" void kernel_launch(void* const* d_in, const int* in_sizes, int n_in,
                              void* d_out, int out_size, void* d_ws, size_t ws_size,
                              hipStream_t stream)
{
    const float* x   = (const float*)d_in[0];
    const float* pos = (const float*)d_in[1];
    const float* W1  = (const float*)d_in[2];
    const float* b1  = (const float*)d_in[3];
    const float* W2  = (const float*)d_in[4];
    const float* b2  = (const float*)d_in[5];  (void)b2;  // cancels in softmax
    const float* Wv  = (const float*)d_in[6];
    float* out = (float*)d_out;
    float* ws = (float*)d_ws;

    float* Aq = ws;                 // B*T*C = 262144
    float* Ak = ws + 262144;        // 262144
    float* V  = ws + 524288;        // B*T*HS = 131072

    k_prep<<<dim3(256), dim3(640), 0, stream>>>(x, pos, W1, b1, Wv, Aq, Ak, V);
    k_fused<<<dim3(2048), dim3(256), 0, stream>>>(Aq, Ak, V, W2, out);
}

// Round 10
// 33.712 us; speedup vs baseline: 2.4310x; 1.5462x over previous
//
#include <hip/hip_runtime.h>
#include <math.h>

#define B_ 4
#define T_ 512
#define C_ 128
#define HS_ 64

typedef float f4 __attribute__((ext_vector_type(4)));
typedef float f2 __attribute__((ext_vector_type(2)));

// scale = C^-0.5
#define SCALE_ 0.08838834764831845f

static __device__ __forceinline__ f2 relu2(f2 v) {
    v.x = fmaxf(v.x, 0.f);
    v.y = fmaxf(v.y, 0.f);
    return v;
}

// ---------------------------------------------------------------------------
// Kernel 1: prep.  x1 = x + pos_emb;  Aq = x1@W1q + b1;  AkT = (x1@W1k)^T;
// V = x@Wv.  256 blocks x 640 threads, block = 8 rows, thread = 1 row x 4 cols.
// Ak is stored TRANSPOSED as AkT[b][c][j] so k_fused's c-loop is coalesced
// over j. Scatter cost: 4 dword stores/thread, 8-lane 32B chunks -> ~8 lines
// per instr, 1MB total.
// ---------------------------------------------------------------------------
__global__ __launch_bounds__(640) void k_prep(
    const float* __restrict__ x, const float* __restrict__ pos,
    const float* __restrict__ W1, const float* __restrict__ b1,
    const float* __restrict__ Wv,
    float* __restrict__ Aq, float* __restrict__ AkT, float* __restrict__ V)
{
    __shared__ float x1s[8 * 132];
    __shared__ float xs[8 * 132];
    const int t = threadIdx.x;
    const int row0 = blockIdx.x * 8;  // over B*T = 2048

    if (t < 256) {
        int r = t >> 5, cq = t & 31;
        int gr = row0 + r;
        f4 xv = *(const f4*)(x + gr * 128 + cq * 4);
        f4 pv = *(const f4*)(pos + (gr & 511) * 128 + cq * 4);
        *(f4*)&xs[r * 132 + cq * 4] = xv;
        *(f4*)&x1s[r * 132 + cq * 4] = xv + pv;
    }
    __syncthreads();

    const int q = t >> 3;   // 0..79 col-quad
    const int r = t & 7;    // row in tile

    const float* wbase;
    int wstr, col0;
    const float* xb;
    f4 binit = {0.f, 0.f, 0.f, 0.f};
    if (q < 32) {
        col0 = q * 4;
        wbase = W1 + 128 * 128 + col0;  // W1q rows (c-major)
        wstr = 128;
        xb = x1s;
        binit = *(const f4*)(b1 + col0);
    } else if (q < 64) {
        col0 = (q - 32) * 4;
        wbase = W1 + col0;  // W1k rows
        wstr = 128;
        xb = x1s;
    } else {
        col0 = (q - 64) * 4;
        wbase = Wv + col0;
        wstr = 64;
        xb = xs;
    }

    f4 acc = binit;
    const float* xr = xb + r * 132;
#pragma unroll 8
    for (int c = 0; c < 128; ++c) {
        f4 w = *(const f4*)(wbase + c * wstr);
        acc += xr[c] * w;
    }

    const int gr = row0 + r;
    if (q < 32) {
        *(f4*)(Aq + (size_t)gr * 128 + col0) = acc;
    } else if (q < 64) {
        const int bb = gr >> 9, j = gr & 511;
        float* base = AkT + ((size_t)bb * 128 + col0) * 512 + j;
        base[0]    = acc.x;
        base[512]  = acc.y;
        base[1024] = acc.z;
        base[1536] = acc.w;
    } else {
        *(f4*)(V + (size_t)gr * 64 + col0) = acc;
    }
}

// ---------------------------------------------------------------------------
// Kernel 2 (v2): fused wei + causal softmax + PV, shuffle-free inner loop.
// Block = 256 thr = 4 waves; block owns a ROW PAIR (r0,r1) of one batch.
// Wave w owns j-window [w*128, w*128+128), lane holds 2 j's (f2).
// S: 128-step c-loop; AkT load = 512B coalesced/instr; Aq[row][c], W2[c]
//    are wave-uniform (scalar-pipe). NO cross-lane ops in the loop.
// Softmax: flat per-window (12 shfl/row TOTAL), p -> LDS.
// PV: V loads shared across both rows; acc[h=lane].
// Merge: 4-window flash-combine via LDS, one barrier. b2 cancels.
// ---------------------------------------------------------------------------
__global__ __launch_bounds__(256) void k_fused(
    const float* __restrict__ Aq, const float* __restrict__ AkT,
    const float* __restrict__ V, const float* __restrict__ W2,
    float* __restrict__ out)
{
    __shared__ float pbuf[4][2][128];
    __shared__ float accs[4][2][64];
    __shared__ float mls[4][2][2];

    const int t = threadIdx.x;
    const int w = t >> 6;
    const int lane = t & 63;
    const int bx = blockIdx.x;        // 0..1023
    const int b = bx & 3;
    const int g = 255 - (bx >> 2);    // descending: heavy pairs first
    const int r0 = g * 2, r1 = g * 2 + 1;

    const int j0 = w * 128 + lane * 2;

    float m0 = -1e30f, m1 = -1e30f, l0 = 0.f, l1 = 0.f;
    float a0 = 0.f, a1 = 0.f;

    if (w * 128 <= r1) {  // wave has at least one valid j for row r1
        const bool act0 = (w * 128 <= r0);

        // ---- S over this wave's 128-j window, both rows ----
        const float* aq0 = Aq + (size_t)(b * T_ + r0) * C_;
        const float* aq1 = aq0 + C_;
        const float* akt = AkT + (size_t)b * C_ * T_ + j0;
        f2 s0a = {0.f, 0.f}, s0b = {0.f, 0.f};
        f2 s1a = {0.f, 0.f}, s1b = {0.f, 0.f};
#pragma unroll 4
        for (int c = 0; c < 128; c += 2) {
            f2 k0 = *(const f2*)(akt + (size_t)c * 512);
            f2 k1 = *(const f2*)(akt + (size_t)(c + 1) * 512);
            const float q00 = aq0[c], q01 = aq0[c + 1];
            const float q10 = aq1[c], q11 = aq1[c + 1];
            const float w0 = W2[c], w1 = W2[c + 1];
            s0a += relu2(k0 + q00) * w0;
            s0b += relu2(k1 + q01) * w1;
            s1a += relu2(k0 + q10) * w0;
            s1b += relu2(k1 + q11) * w1;
        }
        const f2 s0 = (s0a + s0b) * SCALE_;
        const f2 s1 = (s1a + s1b) * SCALE_;

        // causal mask per element
        const float s00 = (j0     <= r0) ? s0.x : -1e30f;
        const float s01 = (j0 + 1 <= r0) ? s0.y : -1e30f;
        const float s10 = (j0     <= r1) ? s1.x : -1e30f;
        const float s11 = (j0 + 1 <= r1) ? s1.y : -1e30f;

        // per-row window max (6 shfl each)
        float t0 = fmaxf(s00, s01), t1 = fmaxf(s10, s11);
#pragma unroll
        for (int off = 1; off < 64; off <<= 1) {
            t0 = fmaxf(t0, __shfl_xor(t0, off));
            t1 = fmaxf(t1, __shfl_xor(t1, off));
        }
        // exp; act0-guard avoids exp(-inf - -inf) when row0 has no valid j
        const float p00 = act0 ? __expf(s00 - t0) : 0.f;
        const float p01 = act0 ? __expf(s01 - t0) : 0.f;
        const float p10 = __expf(s10 - t1);
        const float p11 = __expf(s11 - t1);
        m0 = act0 ? t0 : -1e30f;
        m1 = t1;

        pbuf[w][0][lane * 2]     = p00;
        pbuf[w][0][lane * 2 + 1] = p01;
        pbuf[w][1][lane * 2]     = p10;
        pbuf[w][1][lane * 2 + 1] = p11;

        float ls0 = p00 + p01, ls1 = p10 + p11;
#pragma unroll
        for (int off = 1; off < 64; off <<= 1) {
            ls0 += __shfl_xor(ls0, off);
            ls1 += __shfl_xor(ls1, off);
        }
        l0 = ls0;
        l1 = ls1;

        // ---- PV over window: V loads shared by both rows; lane = h ----
        const float* vt = V + (size_t)b * T_ * HS_ + (size_t)(w * 128) * HS_ + lane;
        float a0e = 0.f, a0o = 0.f, a1e = 0.f, a1o = 0.f;
#pragma unroll 4
        for (int q8 = 0; q8 < 32; ++q8) {
            f4 p0 = *(const f4*)&pbuf[w][0][q8 * 4];
            f4 p1 = *(const f4*)&pbuf[w][1][q8 * 4];
            const float v0 = vt[(q8 * 4 + 0) * HS_];
            const float v1 = vt[(q8 * 4 + 1) * HS_];
            const float v2 = vt[(q8 * 4 + 2) * HS_];
            const float v3 = vt[(q8 * 4 + 3) * HS_];
            a0e += p0.x * v0 + p0.z * v2;
            a0o += p0.y * v1 + p0.w * v3;
            a1e += p1.x * v0 + p1.z * v2;
            a1o += p1.y * v1 + p1.w * v3;
        }
        a0 = a0e + a0o;
        a1 = a1e + a1o;
    }

    // ---- write partials (inactive waves write zeros) & merge ----
    accs[w][0][lane] = a0;
    accs[w][1][lane] = a1;
    if (lane == 0) {
        mls[w][0][0] = m0; mls[w][0][1] = l0;
        mls[w][1][0] = m1; mls[w][1][1] = l1;
    }
    __syncthreads();

    if (w < 2) {
        const int r = w ? r1 : r0;
        const float ma = mls[0][w][0], mb = mls[1][w][0];
        const float mc = mls[2][w][0], md = mls[3][w][0];
        const float ms = fmaxf(fmaxf(ma, mb), fmaxf(mc, md));
        const float ea = __expf(ma - ms), eb = __expf(mb - ms);
        const float ec = __expf(mc - ms), ed = __expf(md - ms);
        const float num = accs[0][w][lane] * ea + accs[1][w][lane] * eb +
                          accs[2][w][lane] * ec + accs[3][w][lane] * ed;
        const float den = mls[0][w][1] * ea + mls[1][w][1] * eb +
                          mls[2][w][1] * ec + mls[3][w][1] * ed;
        out[(size_t)(b * T_ + r) * HS_ + lane] = num / den;
    }
}

// ---------------------------------------------------------------------------
extern "C" void kernel_launch(void* const* d_in, const int* in_sizes, int n_in,
                              void* d_out, int out_size, void* d_ws, size_t ws_size,
                              hipStream_t stream)
{
    const float* x   = (const float*)d_in[0];
    const float* pos = (const float*)d_in[1];
    const float* W1  = (const float*)d_in[2];
    const float* b1  = (const float*)d_in[3];
    const float* W2  = (const float*)d_in[4];
    const float* b2  = (const float*)d_in[5];  (void)b2;  // cancels in softmax
    const float* Wv  = (const float*)d_in[6];
    float* out = (float*)d_out;
    float* ws = (float*)d_ws;

    float* Aq  = ws;                 // B*T*C = 262144
    float* AkT = ws + 262144;        // B*C*T = 262144 (transposed)
    float* V   = ws + 524288;        // B*T*HS = 131072

    k_prep<<<dim3(256), dim3(640), 0, stream>>>(x, pos, W1, b1, Wv, Aq, AkT, V);
    k_fused<<<dim3(1024), dim3(256), 0, stream>>>(Aq, AkT, V, W2, out);
}